// Round 6
// baseline (1852.482 us; speedup 1.0000x reference)
//
#include <hip/hip_runtime.h>
#include <hip/hip_bf16.h>

#define NTOK 16384
#define HD   4096
#define NE   64
#define SL   68                 // logits LDS row stride (floats)

// ws float offsets: W2 = pre-split W_gate, lane-major fragment chunk order
#define W2HI_OFF 256            // 32768 chunks * 8 bf16 = 131072 floats
#define W2LO_OFF (W2HI_OFF + 131072)

typedef __bf16 bf16x8 __attribute__((ext_vector_type(8)));
typedef float  f32x4  __attribute__((ext_vector_type(4)));

__device__ __forceinline__ f32x4 mfma16(bf16x8 a, bf16x8 b, f32x4 c) {
    return __builtin_amdgcn_mfma_f32_16x16x32_bf16(a, b, c, 0, 0, 0);
}

__device__ __forceinline__ void gl_lds16(const float* g, float* l) {
    __builtin_amdgcn_global_load_lds(
        (const __attribute__((address_space(1))) void*)g,
        (__attribute__((address_space(3))) void*)l, 16, 0, 0);
}

// W_gate fp32 -> bf16 hi/lo planes, lane-major chunk order (verified R4/R5):
// chunk idx = ks*2048 + (s*4+j)*64 + lane ; expert = j*16 + (lane&15) ;
// k = ks*256 + s*32 + (lane>>4)*8.  Also zeroes reduction scalars ws[0..129).
__global__ void prep_kernel(const float* __restrict__ Wg, float* __restrict__ ws) {
    const int idx = blockIdx.x * 256 + threadIdx.x;   // 0..32767
    if (blockIdx.x == 0 && threadIdx.x < 129) ws[threadIdx.x] = 0.0f;
    const int ln = idx & 63;
    const int j  = (idx >> 6) & 3;
    const int s  = (idx >> 8) & 7;
    const int ks = idx >> 11;
    const int e  = j * 16 + (ln & 15);
    const int k  = ks * 256 + s * 32 + (ln >> 4) * 8;
    const float* src = Wg + (size_t)e * HD + k;
    float4 q0 = *(const float4*)src;
    float4 q1 = *(const float4*)(src + 4);
    float xs[8] = {q0.x, q0.y, q0.z, q0.w, q1.x, q1.y, q1.z, q1.w};
    bf16x8 hi, lo;
    #pragma unroll
    for (int t = 0; t < 8; ++t) {
        __bf16 h = (__bf16)xs[t];
        hi[t] = h;
        lo[t] = (__bf16)(xs[t] - (float)h);
    }
    *((bf16x8*)((__bf16*)(ws + W2HI_OFF)) + idx) = hi;
    *((bf16x8*)((__bf16*)(ws + W2LO_OFF)) + idx) = lo;
}

// grid 512 x 256 thr: block = 32 tokens x full K. Wave j owns experts j*16..j*16+15.
// K-loop: 32 slices of K=128. A: global_load_lds dbuf (XOR-swizzled granules).
// B: register slice-prefetch from L2, issued BEFORE barrier/A-DMA (vmcnt order).
__global__ __launch_bounds__(256, 2) void router_kernel(
    const float* __restrict__ hs,
    float* __restrict__ out,
    float* __restrict__ ws)
{
    __shared__ __align__(16) float sA[2][4096];   // 2 x 16 KB A slices
    __shared__ float sLog[32 * SL];
    __shared__ float sInv[32];
    __shared__ float sPp[256];
    __shared__ float sCnt[64];
    __shared__ float sZ;

    const int tid  = threadIdx.x;
    const int t0   = blockIdx.x * 32;
    const int wv   = tid >> 6;          // expert group j
    const int lane = tid & 63;
    const int fm   = lane & 15;
    const int fq   = lane >> 4;

    if (tid < 64) sCnt[tid] = 0.0f;
    if (tid == 0) sZ = 0.0f;

    const bf16x8* Whi = (const bf16x8*)((const __bf16*)(ws + W2HI_OFF));
    const bf16x8* Wlo = (const bf16x8*)((const __bf16*)(ws + W2LO_OFF));
    const int cbase = wv * 64 + lane;   // + (kk>>3)*2048 + (kk&7)*256

    // A-DMA per-thread mapping: issue i stages slot S=(i*4+wv)*64+lane;
    // token t=S>>5, granule slot q=S&31 holds global granule q^(t&7).
    const float* aG[4];
    int ldsoff[4];
    #pragma unroll
    for (int i = 0; i < 4; ++i) {
        const int S = (i * 4 + wv) * 64 + lane;
        const int t = S >> 5, q = S & 31;
        aG[i] = hs + (size_t)(t0 + t) * HD + ((q ^ (t & 7)) << 2);
        ldsoff[i] = (i * 4 + wv) * 256;   // wave-uniform float offset
    }

    f32x4 acc[2];
    acc[0] = (f32x4){0.f, 0.f, 0.f, 0.f};
    acc[1] = (f32x4){0.f, 0.f, 0.f, 0.f};

    bf16x8 bufBh[2][4], bufBl[2][4];

    // ---- prologue: B(slice0) regs, then A-DMA(slice0) -> sA[0]
    #pragma unroll
    for (int s = 0; s < 4; ++s) {
        const int ci = (s >> 3) * 2048 + (s & 7) * 256 + cbase;  // kk = s
        bufBh[0][s] = Whi[ci];
        bufBl[0][s] = Wlo[ci];
    }
    #pragma unroll
    for (int i = 0; i < 4; ++i) gl_lds16(aG[i], &sA[0][ldsoff[i]]);

    #pragma unroll 1
    for (int sl = 0; sl < 32; ++sl) {
        const int cur = sl & 1;
        // B prefetch for slice sl+1 (BEFORE barrier & next A-DMA: older in queue)
        if (sl < 31) {
            #pragma unroll
            for (int s = 0; s < 4; ++s) {
                const int kk = (sl + 1) * 4 + s;
                const int ci = (kk >> 3) * 2048 + (kk & 7) * 256 + cbase;
                bufBh[cur ^ 1][s] = Whi[ci];
                bufBl[cur ^ 1][s] = Wlo[ci];
            }
        }
        __syncthreads();   // drains A-DMA(sl) [the HBM pacing] + B(sl+1) residual
        if (sl < 31) {
            #pragma unroll
            for (int i = 0; i < 4; ++i)
                gl_lds16(aG[i] + (sl + 1) * 128, &sA[cur ^ 1][ldsoff[i]]);
        }
        // compute slice sl from sA[cur] + bufB[cur]
        #pragma unroll
        for (int s = 0; s < 4; ++s) {
            #pragma unroll
            for (int mt = 0; mt < 2; ++mt) {
                const int t = mt * 16 + fm;
                const int g0 = s * 8 + fq * 2;
                const int base = t * 128;
                f32x4 qa = *(const f32x4*)&sA[cur][base + ((g0    ) ^ (t & 7)) * 4];
                f32x4 qb = *(const f32x4*)&sA[cur][base + ((g0 + 1) ^ (t & 7)) * 4];
                float xs[8] = {qa.x, qa.y, qa.z, qa.w, qb.x, qb.y, qb.z, qb.w};
                bf16x8 ahi, alo;
                #pragma unroll
                for (int e = 0; e < 8; ++e) {
                    __bf16 h = (__bf16)xs[e];
                    ahi[e] = h;
                    alo[e] = (__bf16)(xs[e] - (float)h);
                }
                acc[mt] = mfma16(ahi, bufBh[cur][s], acc[mt]);
                acc[mt] = mfma16(alo, bufBh[cur][s], acc[mt]);
                acc[mt] = mfma16(ahi, bufBl[cur][s], acc[mt]);
                acc[mt] = mfma16(alo, bufBl[cur][s], acc[mt]);
            }
        }
    }

    // ---- logits to LDS: C/D col=fm (expert within group), row=fq*4+r (token)
    #pragma unroll
    for (int mt = 0; mt < 2; ++mt)
        #pragma unroll
        for (int r = 0; r < 4; ++r) {
            const int tok = mt * 16 + fq * 4 + r;
            sLog[tok * SL + wv * 16 + fm] = acc[mt][r];
        }
    __syncthreads();

    // ---- softmax/top-2 (R2-verified shape): 8 lanes/token, 8 experts/lane
    const int g = tid >> 3;       // token 0..31
    const int l = tid & 7;
    float* Lrow = &sLog[g * SL + l * 8];
    float lv[8];
    float m = -3.0e38f;
    #pragma unroll
    for (int c = 0; c < 8; ++c) { lv[c] = Lrow[c]; m = fmaxf(m, lv[c]); }
    m = fmaxf(m, __shfl_xor(m, 1, 64));
    m = fmaxf(m, __shfl_xor(m, 2, 64));
    m = fmaxf(m, __shfl_xor(m, 4, 64));

    float v1 = -3.0e38f, v2 = -3.0e38f; int i1 = 0, i2 = 0;
    float ssum = 0.0f;
    #pragma unroll
    for (int c = 0; c < 8; ++c) {
        const float val = lv[c]; const int idx = l * 8 + c;
        const float ev = __expf(val - m);
        Lrow[c] = ev;
        ssum += ev;
        if (val > v1) { v2 = v1; i2 = i1; v1 = val; i1 = idx; }
        else if (val > v2) { v2 = val; i2 = idx; }
    }
    ssum += __shfl_xor(ssum, 1, 64);
    ssum += __shfl_xor(ssum, 2, 64);
    ssum += __shfl_xor(ssum, 4, 64);

    #pragma unroll
    for (int s = 1; s <= 4; s <<= 1) {
        const float ov1 = __shfl_xor(v1, s, 64);
        const int   oi1 = __shfl_xor(i1, s, 64);
        const float ov2 = __shfl_xor(v2, s, 64);
        const int   oi2 = __shfl_xor(i2, s, 64);
        float n1, n2; int ni1, ni2;
        const bool ofirst = (ov1 > v1) || (ov1 == v1 && oi1 < i1);
        if (ofirst) {
            n1 = ov1; ni1 = oi1;
            const bool osec = (ov2 > v1) || (ov2 == v1 && oi2 < i1);
            n2 = osec ? ov2 : v1; ni2 = osec ? oi2 : i1;
        } else {
            n1 = v1; ni1 = i1;
            const bool asec = (v2 > ov1) || (v2 == ov1 && i2 < oi1);
            n2 = asec ? v2 : ov1; ni2 = asec ? i2 : oi1;
        }
        v1 = n1; i1 = ni1; v2 = n2; i2 = ni2;
    }

    if (l == 0) {
        const float e1 = __expf(v1 - m), e2 = __expf(v2 - m);
        const float winv = 1.0f / (e1 + e2);
        const int token = t0 + g;
        out[2 * token]     = e1 * winv;
        out[2 * token + 1] = e2 * winv;
        out[2 * NTOK + 2 * token]     = (float)i1;   // indices as f32 (concat promotion)
        out[2 * NTOK + 2 * token + 1] = (float)i2;
        const float lse = m + __logf(ssum);
        atomicAdd(&sZ, lse * lse);
        atomicAdd(&sCnt[i1], 1.0f);
        atomicAdd(&sCnt[i2], 1.0f);
        sInv[g] = 1.0f / ssum;
    }
    __syncthreads();

    // ---- per-expert prob sums over 32 tokens, then global atomics
    {
        const int e = tid & 63;
        const int q = tid >> 6;
        float p = 0.0f;
        #pragma unroll
        for (int t = 0; t < 8; ++t) {
            const int tk = q * 8 + t;
            p += sLog[tk * SL + e] * sInv[tk];
        }
        sPp[q * 64 + e] = p;
    }
    __syncthreads();
    if (tid < 64) {
        const float ps = sPp[tid] + sPp[64 + tid] + sPp[128 + tid] + sPp[192 + tid];
        atomicAdd(&ws[tid], ps);             // sum of probs per expert
        atomicAdd(&ws[64 + tid], sCnt[tid]); // top-2 counts per expert
    }
    if (tid == 0) atomicAdd(&ws[128], sZ);
}

__global__ void finalize_kernel(const float* __restrict__ ws, float* __restrict__ out) {
    const int e = threadIdx.x;   // 64 threads, one wave
    const float P = ws[e] * (1.0f / NTOK);
    const float f = ws[64 + e] * (1.0f / (NTOK * 2));
    float term = f * P;
    #pragma unroll
    for (int s = 32; s >= 1; s >>= 1) term += __shfl_xor(term, s, 64);
    if (e == 0) {
        const float lb = 64.0f * term;
        const float z  = ws[128] * (1.0f / NTOK);
        out[4 * NTOK] = 0.001f * lb + 0.001f * z;
    }
}

extern "C" void kernel_launch(void* const* d_in, const int* in_sizes, int n_in,
                              void* d_out, int out_size, void* d_ws, size_t ws_size,
                              hipStream_t stream) {
    const float* hs = (const float*)d_in[0];
    const float* Wg = (const float*)d_in[1];
    float* out = (float*)d_out;
    float* ws  = (float*)d_ws;

    hipLaunchKernelGGL(prep_kernel, dim3(128), dim3(256), 0, stream, Wg, ws);
    hipLaunchKernelGGL(router_kernel, dim3(NTOK / 32), dim3(256), 0, stream, hs, out, ws);
    hipLaunchKernelGGL(finalize_kernel, dim3(1), dim3(64), 0, stream, ws, out);
}